// Round 1
// baseline (307.067 us; speedup 1.0000x reference)
//
#include <hip/hip_runtime.h>

#define BB 8
#define HH 1024
#define WW 1280
#define HW (HH * WW)
#define EPSF 1e-7f

typedef float f4 __attribute__((ext_vector_type(4)));

__device__ __forceinline__ float fast_rcp(float x) {
    float r = __builtin_amdgcn_rcpf(x);
    // one Newton-Raphson step -> ~1 ulp
    r = r * __builtin_fmaf(-x, r, 2.0f);
    return r;
}

__global__ __launch_bounds__(320) void synth_view_kernel(
    const float* __restrict__ img, const float* __restrict__ disp,
    const float* __restrict__ srcK, const float* __restrict__ tgtK,
    const float* __restrict__ trans, float* __restrict__ out)
{
    const int tx = threadIdx.x;      // 0..319
    const int xp = tx << 2;          // 4 pixels per thread, 320*4 = 1280 = WW
    const int y  = blockIdx.y;
    const int b  = blockIdx.z;

    // wave-uniform -> scalar loads
    const float* sK = srcK + b * 16;
    const float* tK = tgtK + b * 16;
    const float* tv = trans + b * 3;

    const float fsx = sK[0], csx = sK[2];
    const float fsy = sK[5], csy = sK[6];
    const float ftx = tK[0], ctx = tK[2];
    const float fty = tK[5], cty = tK[6];
    const float t0 = tv[0], t1 = tv[1], t2 = tv[2];

    // Closed-form: K has last row [0,0,1], R = I.
    //   cp.x = (ftx*(x-csx)/fsx + ctx)*depth + (ftx*t0 + ctx*t2)
    //   cp.y = (fty*(y-csy)/fsy + cty)*depth + (fty*t1 + cty*t2)
    //   cp.z = depth + t2
    // px = cp.x/(cp.z+eps); multiply num+den by sd=1/depth:
    //   px = (A00*x + A02 + C0*sd) / (1 + (t2+eps)*sd)
    // sx = px*W/(W-1) - 0.5  (scale folded into A/C constants)
    const float Sx = (float)WW / (float)(WW - 1);
    const float Sy = (float)HH / (float)(HH - 1);
    const float rfsx = fast_rcp(fsx);
    const float rfsy = fast_rcp(fsy);
    const float A00 = ftx * rfsx * Sx;
    const float A02 = __builtin_fmaf(-ftx * csx, rfsx, ctx) * Sx;
    const float C0  = (ftx * t0 + ctx * t2) * Sx;
    const float A11 = fty * rfsy * Sy;
    const float A12 = __builtin_fmaf(-fty * csy, rfsy, cty) * Sy;
    const float C1  = (fty * t1 + cty * t2) * Sy;
    const float t2e = t2 + EPSF;

    const float ay = __builtin_fmaf(A11, (float)y, A12);   // row-invariant

    const int rowoff = y * WW + xp;
    const f4 d4 = __builtin_nontemporal_load(
        reinterpret_cast<const f4*>(disp + b * HW + rowoff));

    const float mind = 1.0f / 255.0f;
    const float rng  = 0.1f - mind;     // max_disp - min_disp

    const float dk[4] = { d4.x, d4.y, d4.z, d4.w };
    float w00[4], w01[4], w10[4], w11[4];
    int   o00[4], o01[4], o10[4], o11[4];

#pragma unroll
    for (int k = 0; k < 4; ++k) {       // static indices after unroll
        const float sd = __builtin_fmaf(dk[k], rng, mind);
        const float r  = fast_rcp(__builtin_fmaf(t2e, sd, 1.0f));
        const float ax = __builtin_fmaf(A00, (float)(xp + k), A02);
        const float sx = __builtin_fmaf(__builtin_fmaf(C0, sd, ax), r, -0.5f);
        const float sy = __builtin_fmaf(__builtin_fmaf(C1, sd, ay), r, -0.5f);

        const float xf = floorf(sx), yf = floorf(sy);
        const float wx = sx - xf, wy = sy - yf;
        const int ix = (int)xf, iy = (int)yf;
        const int x0 = min(max(ix,     0), WW - 1);
        const int x1 = min(max(ix + 1, 0), WW - 1);
        const int y0 = min(max(iy,     0), HH - 1);
        const int y1 = min(max(iy + 1, 0), HH - 1);
        o00[k] = y0 * WW + x0;
        o01[k] = y0 * WW + x1;
        o10[k] = y1 * WW + x0;
        o11[k] = y1 * WW + x1;
        const float wxm = 1.0f - wx, wym = 1.0f - wy;
        w00[k] = wxm * wym; w01[k] = wx * wym;
        w10[k] = wxm * wy;  w11[k] = wx * wy;
    }

    const float* imb  = img + b * (3 * HW);
    float*       outb = out + b * (3 * HW) + rowoff;

#pragma unroll
    for (int c = 0; c < 3; ++c) {
        const float* ic = imb + c * HW;
        float v[4];
#pragma unroll
        for (int k = 0; k < 4; ++k) {
            float acc =          ic[o00[k]] * w00[k];
            acc = __builtin_fmaf(ic[o01[k]], w01[k], acc);
            acc = __builtin_fmaf(ic[o10[k]], w10[k], acc);
            acc = __builtin_fmaf(ic[o11[k]], w11[k], acc);
            v[k] = acc;
        }
        f4 v4 = { v[0], v[1], v[2], v[3] };
        __builtin_nontemporal_store(v4, reinterpret_cast<f4*>(outb + c * HW));
    }
}

extern "C" void kernel_launch(void* const* d_in, const int* in_sizes, int n_in,
                              void* d_out, int out_size, void* d_ws, size_t ws_size,
                              hipStream_t stream) {
    const float* img   = (const float*)d_in[0];
    const float* disp  = (const float*)d_in[1];
    const float* srcK  = (const float*)d_in[2];
    const float* tgtK  = (const float*)d_in[3];
    const float* trans = (const float*)d_in[4];
    float* out = (float*)d_out;

    dim3 block(320, 1, 1);               // 5 waves; 320*4 px = one full row
    dim3 grid(1, HH, BB);
    synth_view_kernel<<<grid, block, 0, stream>>>(img, disp, srcK, tgtK, trans, out);
}

// Round 2
// 248.334 us; speedup vs baseline: 1.2365x; 1.2365x over previous
//
#include <hip/hip_runtime.h>

#define BB 8
#define HH 1024
#define WW 1280
#define HW (HH * WW)
#define EPSF 1e-7f

__device__ __forceinline__ float fast_rcp(float x) {
    float r = __builtin_amdgcn_rcpf(x);
    r = r * __builtin_fmaf(-x, r, 2.0f);   // one NR step -> ~1 ulp
    return r;
}

__global__ __launch_bounds__(256) void synth_view_kernel(
    const float* __restrict__ img, const float* __restrict__ disp,
    const float* __restrict__ srcK, const float* __restrict__ tgtK,
    const float* __restrict__ trans, float* __restrict__ out)
{
    const int x = blockIdx.x * 256 + threadIdx.x;
    const int y = blockIdx.y;
    const int b = blockIdx.z;

    // wave-uniform -> scalar loads
    const float* sK = srcK + b * 16;
    const float* tK = tgtK + b * 16;
    const float* tv = trans + b * 3;

    const float fsx = sK[0], csx = sK[2];
    const float fsy = sK[5], csy = sK[6];
    const float ftx = tK[0], ctx = tK[2];
    const float fty = tK[5], cty = tK[6];
    const float t0 = tv[0], t1 = tv[1], t2 = tv[2];

    // Closed form (K last row = [0,0,1], R = I):
    //   px = (A00*x + A02 + C0*sd) / (1 + (t2+eps)*sd),  sd = scaled_disp = 1/depth
    //   sx = px*W/(W-1) - 0.5   (scale folded into A/C)
    const float Sx = (float)WW / (float)(WW - 1);
    const float Sy = (float)HH / (float)(HH - 1);
    const float rfsx = fast_rcp(fsx);
    const float rfsy = fast_rcp(fsy);
    const float A00 = ftx * rfsx * Sx;
    const float A02 = __builtin_fmaf(-ftx * csx, rfsx, ctx) * Sx;
    const float C0  = (ftx * t0 + ctx * t2) * Sx;
    const float A11 = fty * rfsy * Sy;
    const float A12 = __builtin_fmaf(-fty * csy, rfsy, cty) * Sy;
    const float C1  = (fty * t1 + cty * t2) * Sy;
    const float t2e = t2 + EPSF;

    const int rowoff = y * WW + x;
    const float dsp = __builtin_nontemporal_load(disp + b * HW + rowoff);

    const float mind = 1.0f / 255.0f;
    const float rng  = 0.1f - mind;          // max_disp - min_disp
    const float sd   = __builtin_fmaf(dsp, rng, mind);
    const float r    = fast_rcp(__builtin_fmaf(t2e, sd, 1.0f));

    const float ax = __builtin_fmaf(A00, (float)x, A02);
    const float ay = __builtin_fmaf(A11, (float)y, A12);
    const float sx = __builtin_fmaf(__builtin_fmaf(C0, sd, ax), r, -0.5f);
    const float sy = __builtin_fmaf(__builtin_fmaf(C1, sd, ay), r, -0.5f);

    const float xf = floorf(sx), yf = floorf(sy);
    const float wx = sx - xf,    wy = sy - yf;
    const int ix = (int)xf, iy = (int)yf;
    const int x0 = min(max(ix,     0), WW - 1);
    const int x1 = min(max(ix + 1, 0), WW - 1);
    const int y0 = min(max(iy,     0), HH - 1);
    const int y1 = min(max(iy + 1, 0), HH - 1);

    const int o00 = y0 * WW + x0;
    const int o01 = y0 * WW + x1;
    const int o10 = y1 * WW + x0;
    const int o11 = y1 * WW + x1;

    const float wxm = 1.0f - wx, wym = 1.0f - wy;
    const float w00 = wxm * wym, w01 = wx * wym;
    const float w10 = wxm * wy,  w11 = wx * wy;

    const float* imb  = img + b * (3 * HW);
    float*       outb = out + b * (3 * HW) + rowoff;

#pragma unroll
    for (int c = 0; c < 3; ++c) {
        const float* ic = imb + c * HW;
        float acc =          ic[o00] * w00;
        acc = __builtin_fmaf(ic[o01], w01, acc);
        acc = __builtin_fmaf(ic[o10], w10, acc);
        acc = __builtin_fmaf(ic[o11], w11, acc);
        __builtin_nontemporal_store(acc, outb + c * HW);
    }
}

extern "C" void kernel_launch(void* const* d_in, const int* in_sizes, int n_in,
                              void* d_out, int out_size, void* d_ws, size_t ws_size,
                              hipStream_t stream) {
    const float* img   = (const float*)d_in[0];
    const float* disp  = (const float*)d_in[1];
    const float* srcK  = (const float*)d_in[2];
    const float* tgtK  = (const float*)d_in[3];
    const float* trans = (const float*)d_in[4];
    float* out = (float*)d_out;

    dim3 block(256, 1, 1);
    dim3 grid(WW / 256, HH, BB);   // 5 x 1024 x 8 — full TLP, 1 px/thread
    synth_view_kernel<<<grid, block, 0, stream>>>(img, disp, srcK, tgtK, trans, out);
}